// Round 7
// baseline (307.869 us; speedup 1.0000x reference)
//
#include <hip/hip_runtime.h>
#include <hip/hip_bf16.h>
#include <hip/hip_fp16.h>

#define EMBED 640
#define CROSS 768
#define NH 8
#define HEAD 80
#define BATCH 8
#define SEQT 4096
#define SEQS 77
#define MROWS (BATCH * SEQT)

typedef _Float16 half8 __attribute__((ext_vector_type(8)));
typedef float floatx4 __attribute__((ext_vector_type(4)));

__device__ __forceinline__ void lds_load16(const void* g, void* l) {
    __builtin_amdgcn_global_load_lds(
        (const __attribute__((address_space(1))) void*)g,
        (__attribute__((address_space(3))) void*)l, 16, 0, 0);
}

// ---------------------------------------------------------------------------
// All four weight transposes in one launch. z: 0=Wq 1=Wo 2=Wk 3=Wv.
// W [K,N] fp32 -> Wt [N,K] f16 (tiled 32x32).
// ---------------------------------------------------------------------------
__global__ __launch_bounds__(256) void transpose_all(
    const float* __restrict__ Wq, const float* __restrict__ Wo,
    const float* __restrict__ Wk, const float* __restrict__ Wv,
    _Float16* __restrict__ wqt, _Float16* __restrict__ wot,
    _Float16* __restrict__ wkt, _Float16* __restrict__ wvt)
{
    __shared__ float t[32][33];
    const int z = blockIdx.z;
    const float* W;  _Float16* Wt;  int K;
    if      (z == 0) { W = Wq; Wt = wqt; K = EMBED; }
    else if (z == 1) { W = Wo; Wt = wot; K = EMBED; }
    else if (z == 2) { W = Wk; Wt = wkt; K = CROSS; }
    else             { W = Wv; Wt = wvt; K = CROSS; }
    const int N = EMBED;
    const int k0 = blockIdx.y * 32, n0 = blockIdx.x * 32;
    if (k0 >= K) return;
    for (int r = threadIdx.y; r < 32; r += 8)
        t[r][threadIdx.x] = W[(size_t)(k0 + r) * N + n0 + threadIdx.x];
    __syncthreads();
    for (int r = threadIdx.y; r < 32; r += 8)
        Wt[(size_t)(n0 + r) * K + k0 + threadIdx.x] = (_Float16)t[threadIdx.x][r];
}

// ---------------------------------------------------------------------------
// y [616*768] fp32 -> yh [640][768] f16 (rows 616+ zeroed)  AND  vth zero.
// ---------------------------------------------------------------------------
__global__ __launch_bounds__(256) void cvt_y_zero(
    const float* __restrict__ y, _Float16* __restrict__ yh,
    _Float16* __restrict__ vth)
{
    const size_t i = (size_t)blockIdx.x * 256 + threadIdx.x;
    if (i < (size_t)640 * CROSS / 8) {
        const size_t e = i * 8;
        half8 h = {};
        if (e < (size_t)BATCH * SEQS * CROSS) {
            float4 a = *(const float4*)&y[e];
            float4 b = *(const float4*)&y[e + 4];
            h[0] = (_Float16)a.x; h[1] = (_Float16)a.y;
            h[2] = (_Float16)a.z; h[3] = (_Float16)a.w;
            h[4] = (_Float16)b.x; h[5] = (_Float16)b.y;
            h[6] = (_Float16)b.z; h[7] = (_Float16)b.w;
        }
        *(half8*)&yh[e] = h;
    } else {
        const size_t j = (i - (size_t)640 * CROSS / 8) * 8;
        *(half8*)&vth[j] = (half8){};
    }
}

// ---------------------------------------------------------------------------
// f16 MFMA GEMM v6 (O path): C(fp32) = A[M,K] @ Bt[N,K]^T + bias.
// BK=64, double-buffered, stage-first + counted vmcnt(8), 32 MFMA/barrier-pair,
// 8-slot XOR swizzle both-sides, XCD-aware remap, setprio around MFMA.
// ---------------------------------------------------------------------------
template <bool HALF_OUT>
__global__ __launch_bounds__(256) void gemm_f16(
    const _Float16* __restrict__ A,   // [M,K] f16
    const _Float16* __restrict__ Bt,  // [N,K] f16
    const float* __restrict__ bias,
    void* __restrict__ Cout, int M, int N, int K, float scale)
{
    __shared__ _Float16 As[2][128 * 64];
    __shared__ _Float16 Bs[2][128 * 64];

    const int tid  = threadIdx.x;
    const int wave = tid >> 6;
    const int lane = tid & 63;
    const int quad = lane >> 4;
    const int l16  = lane & 15;

    const int l   = blockIdx.y * gridDim.x + blockIdx.x;
    const int inner = l >> 3;
    const int p   = (l & 7) + 8 * (inner / gridDim.x);
    const int nt  = inner % gridDim.x;
    const int m0 = p * 128, n0 = nt * 128;
    const int wm = (wave >> 1) * 64, wn = (wave & 1) * 64;

    const int srow = wave * 32 + (lane >> 3);          // + q*8
    const int sch  = ((lane & 7) ^ (lane >> 3)) * 8;   // pre-swizzled chunk
    const _Float16* gA[4];
    const _Float16* gB[4];
    #pragma unroll
    for (int q = 0; q < 4; ++q) {
        gA[q] = &A [(size_t)(m0 + srow + q * 8) * K + sch];
        gB[q] = &Bt[(size_t)(n0 + srow + q * 8) * K + sch];
    }

    const int NT = K / 64;   // 10

    auto stage = [&](int t, int bf) {
        const size_t off = (size_t)t * 64;
        #pragma unroll
        for (int q = 0; q < 4; ++q) {
            lds_load16(gA[q] + off, &As[bf][(wave * 4 + q) * 512]);
            lds_load16(gB[q] + off, &Bs[bf][(wave * 4 + q) * 512]);
        }
    };
    stage(0, 0);

    floatx4 acc[4][4] = {};

    for (int t = 0; t < NT; ++t) {
        const int bf = t & 1;
        if (t + 1 < NT) {
            stage(t + 1, bf ^ 1);
            asm volatile("s_waitcnt vmcnt(8)" ::: "memory");
        } else {
            asm volatile("s_waitcnt vmcnt(0)" ::: "memory");
        }
        __builtin_amdgcn_s_barrier();
        __builtin_amdgcn_sched_barrier(0);

        const _Float16* as = As[bf];
        const _Float16* bs = Bs[bf];
        __builtin_amdgcn_s_setprio(1);
        #pragma unroll
        for (int k = 0; k < 2; ++k) {
            half8 a[4], b[4];
            #pragma unroll
            for (int i = 0; i < 4; ++i)
                a[i] = *(const half8*)&as[(wm + i * 16 + l16) * 64 +
                                          (((k * 4 + quad) ^ (l16 & 7)) * 8)];
            #pragma unroll
            for (int j = 0; j < 4; ++j)
                b[j] = *(const half8*)&bs[(wn + j * 16 + l16) * 64 +
                                          (((k * 4 + quad) ^ (l16 & 7)) * 8)];
            #pragma unroll
            for (int i = 0; i < 4; ++i)
                #pragma unroll
                for (int j = 0; j < 4; ++j)
                    acc[i][j] = __builtin_amdgcn_mfma_f32_16x16x32_f16(
                        a[i], b[j], acc[i][j], 0, 0, 0);
        }
        __builtin_amdgcn_s_setprio(0);

        asm volatile("s_waitcnt lgkmcnt(0)" ::: "memory");
        __builtin_amdgcn_sched_barrier(0);
        __builtin_amdgcn_s_barrier();
    }

    float bcol[4];
    #pragma unroll
    for (int j = 0; j < 4; ++j) bcol[j] = bias[n0 + wn + j * 16 + l16];
    #pragma unroll
    for (int i = 0; i < 4; ++i)
        #pragma unroll
        for (int r = 0; r < 4; ++r) {
            const int m = m0 + wm + i * 16 + quad * 4 + r;
            #pragma unroll
            for (int j = 0; j < 4; ++j) {
                float v = (acc[i][j][r] + bcol[j]) * scale;
                const size_t off = (size_t)m * N + n0 + wn + j * 16 + l16;
                if (HALF_OUT) ((_Float16*)Cout)[off] = (_Float16)v;
                else          ((float*)Cout)[off] = v;
            }
        }
}

// ---------------------------------------------------------------------------
// Q projection with FUSED fp32->f16 cast of x (v7).
// v6 pipeline shape, but A comes from fp32 x via reg-staging:
//   iter t: issue B(t+1) gload_lds + A(t+1) 8x dwordx4 -> regs (named ping-
//   pong aP/aQ, hand 2-unrolled), wait vmcnt(12) (t's loads landed, t+1 in
//   flight), cvt + 4x ds_write_b128 A(t) into LDS (same 8-slot XOR layout as
//   v6 -> read side unchanged), barrier, 32 MFMA, barrier.
// r4's failure (vmcnt(0) drain each iter) is avoided: loads lead by a full
// iteration (~2400 cyc > 900 cyc HBM latency).
// ---------------------------------------------------------------------------
__global__ __launch_bounds__(256) void gemm_q(
    const float* __restrict__ x,      // [M][EMBED] fp32
    const _Float16* __restrict__ Bt,  // [EMBED][EMBED] f16
    const float* __restrict__ bias,
    _Float16* __restrict__ Cout)      // [M][EMBED] f16, *1/sqrt(80)
{
    constexpr int K = EMBED, N = EMBED;
    __shared__ _Float16 As[2][128 * 64];
    __shared__ _Float16 Bs[2][128 * 64];

    const int tid  = threadIdx.x;
    const int wave = tid >> 6;
    const int lane = tid & 63;
    const int quad = lane >> 4;
    const int l16  = lane & 15;

    const int l   = blockIdx.y * gridDim.x + blockIdx.x;
    const int inner = l >> 3;
    const int p   = (l & 7) + 8 * (inner / gridDim.x);
    const int nt  = inner % gridDim.x;
    const int m0 = p * 128, n0 = nt * 128;
    const int wm = (wave >> 1) * 64, wn = (wave & 1) * 64;

    // B staging via gload_lds (identical contract to v6)
    const int srow = wave * 32 + (lane >> 3);
    const int sch  = ((lane & 7) ^ (lane >> 3)) * 8;
    const _Float16* gB[4];
    #pragma unroll
    for (int q = 0; q < 4; ++q)
        gB[q] = &Bt[(size_t)(n0 + srow + q * 8) * K + sch];

    // A reg staging: row ar = tid>>1, half ah = tid&1 -> 32 fp32 (8 float4).
    // chunk c = ah*4+j goes to LDS slot c ^ (ar&7)  (row r holds chunk s^(r&7)
    // at slot s -> reader's quad^(l16&7) XOR matches, as in v6).
    const int ar = tid >> 1, ah = tid & 1;
    const float* gA = &x[(size_t)(m0 + ar) * K + ah * 32];
    int wslot[4];
    #pragma unroll
    for (int j = 0; j < 4; ++j) wslot[j] = ((ah * 4 + j) ^ (ar & 7)) * 8;

    constexpr int NT = K / 64;   // 10 (even)

    auto stageB = [&](int t, int bf) {
        #pragma unroll
        for (int q = 0; q < 4; ++q)
            lds_load16(gB[q] + (size_t)t * 64, &Bs[bf][(wave * 4 + q) * 512]);
    };
    auto loadA = [&](float4 (&a)[8], int t) {
        #pragma unroll
        for (int j = 0; j < 8; ++j)
            a[j] = *(const float4*)(gA + (size_t)t * 64 + j * 4);
    };
    auto writeA = [&](const float4 (&a)[8], int bf) {
        #pragma unroll
        for (int j = 0; j < 4; ++j) {
            const float4 u = a[2 * j], v = a[2 * j + 1];
            half8 h;
            h[0] = (_Float16)u.x; h[1] = (_Float16)u.y;
            h[2] = (_Float16)u.z; h[3] = (_Float16)u.w;
            h[4] = (_Float16)v.x; h[5] = (_Float16)v.y;
            h[6] = (_Float16)v.z; h[7] = (_Float16)v.w;
            *(half8*)&As[bf][ar * 64 + wslot[j]] = h;
        }
    };

    floatx4 acc[4][4] = {};
    auto compute = [&](int bf) {
        const _Float16* as = As[bf];
        const _Float16* bs = Bs[bf];
        __builtin_amdgcn_s_setprio(1);
        #pragma unroll
        for (int k = 0; k < 2; ++k) {
            half8 a[4], b[4];
            #pragma unroll
            for (int i = 0; i < 4; ++i)
                a[i] = *(const half8*)&as[(wm + i * 16 + l16) * 64 +
                                          (((k * 4 + quad) ^ (l16 & 7)) * 8)];
            #pragma unroll
            for (int j = 0; j < 4; ++j)
                b[j] = *(const half8*)&bs[(wn + j * 16 + l16) * 64 +
                                          (((k * 4 + quad) ^ (l16 & 7)) * 8)];
            #pragma unroll
            for (int i = 0; i < 4; ++i)
                #pragma unroll
                for (int j = 0; j < 4; ++j)
                    acc[i][j] = __builtin_amdgcn_mfma_f32_16x16x32_f16(
                        a[i], b[j], acc[i][j], 0, 0, 0);
        }
        __builtin_amdgcn_s_setprio(0);
    };

    float4 aP[8], aQ[8];     // named ping-pong (rule #20: no runtime index)

    // prologue: tile 0 in flight (12 outstanding)
    stageB(0, 0);
    loadA(aP, 0);

    for (int t = 0; t < NT; t += 2) {
        // even: compute t (buf0, aP); prefetch t+1 (buf1, aQ). t+1 <= 9 < NT.
        stageB(t + 1, 1);
        loadA(aQ, t + 1);
        asm volatile("s_waitcnt vmcnt(12)" ::: "memory");   // t's 12 landed
        __builtin_amdgcn_sched_barrier(0);
        writeA(aP, 0);
        asm volatile("s_waitcnt lgkmcnt(0)" ::: "memory");
        __builtin_amdgcn_sched_barrier(0);
        __builtin_amdgcn_s_barrier();
        __builtin_amdgcn_sched_barrier(0);
        compute(0);
        asm volatile("s_waitcnt lgkmcnt(0)" ::: "memory");
        __builtin_amdgcn_sched_barrier(0);
        __builtin_amdgcn_s_barrier();

        // odd: compute t+1 (buf1, aQ); prefetch t+2 (buf0, aP)
        if (t + 2 < NT) {
            stageB(t + 2, 0);
            loadA(aP, t + 2);
            asm volatile("s_waitcnt vmcnt(12)" ::: "memory");
        } else {
            asm volatile("s_waitcnt vmcnt(0)" ::: "memory");
        }
        __builtin_amdgcn_sched_barrier(0);
        writeA(aQ, 1);
        asm volatile("s_waitcnt lgkmcnt(0)" ::: "memory");
        __builtin_amdgcn_sched_barrier(0);
        __builtin_amdgcn_s_barrier();
        __builtin_amdgcn_sched_barrier(0);
        compute(1);
        asm volatile("s_waitcnt lgkmcnt(0)" ::: "memory");
        __builtin_amdgcn_sched_barrier(0);
        __builtin_amdgcn_s_barrier();
    }

    const float scale = 0.11180339887498949f;   // 1/sqrt(80)
    float bcol[4];
    #pragma unroll
    for (int j = 0; j < 4; ++j) bcol[j] = bias[n0 + wn + j * 16 + l16];
    #pragma unroll
    for (int i = 0; i < 4; ++i)
        #pragma unroll
        for (int r = 0; r < 4; ++r) {
            const int m = m0 + wm + i * 16 + quad * 4 + r;
            #pragma unroll
            for (int j = 0; j < 4; ++j)
                Cout[(size_t)m * N + n0 + wn + j * 16 + l16] =
                    (_Float16)((acc[i][j][r] + bcol[j]) * scale);
        }
}

// ---------------------------------------------------------------------------
// K/V projection via MFMA. 64x64 tiles, 4 waves (wave w = cols w*16..w*16+15).
// ---------------------------------------------------------------------------
__global__ __launch_bounds__(256) void kv_gemm(
    const _Float16* __restrict__ yh,
    const _Float16* __restrict__ Wkt, const _Float16* __restrict__ Wvt,
    const float* __restrict__ bk, const float* __restrict__ bv,
    _Float16* __restrict__ kh, _Float16* __restrict__ vth)
{
    __shared__ _Float16 As[64 * 32];
    __shared__ _Float16 Bs[64 * 32];

    const int tid = threadIdx.x;
    const int wave = tid >> 6, lane = tid & 63;
    const int quad = lane >> 4, l16 = lane & 15;
    const int m0 = blockIdx.y * 64, n0 = blockIdx.x * 64;
    const bool isV = blockIdx.z != 0;
    const _Float16* Bt = isV ? Wvt : Wkt;
    const float* bias  = isV ? bv : bk;

    const int row = tid >> 2;        // 0..63
    const int kch = (tid & 3) * 8;   // k chunk (8 f16 = 16 B)

    floatx4 acc[4] = {};

    for (int k0 = 0; k0 < CROSS; k0 += 32) {
        lds_load16(&yh[(size_t)(m0 + row) * CROSS + k0 + kch], &As[wave * 512]);
        lds_load16(&Bt[(size_t)(n0 + row) * CROSS + k0 + kch], &Bs[wave * 512]);
        __syncthreads();
        half8 b = *(const half8*)&Bs[(wave * 16 + l16) * 32 + quad * 8];
        #pragma unroll
        for (int i = 0; i < 4; ++i) {
            half8 a = *(const half8*)&As[(i * 16 + l16) * 32 + quad * 8];
            acc[i] = __builtin_amdgcn_mfma_f32_16x16x32_f16(a, b, acc[i], 0, 0, 0);
        }
        __syncthreads();
    }

    const int n = n0 + wave * 16 + l16;     // 0..639
    const int h = n / HEAD, d = n % HEAD;
    const float bb = bias[n];
    #pragma unroll
    for (int i = 0; i < 4; ++i)
        #pragma unroll
        for (int r = 0; r < 4; ++r) {
            const int m = m0 + i * 16 + quad * 4 + r;
            if (m >= BATCH * SEQS) continue;
            const int b_ = m / SEQS, s = m % SEQS;
            const int bh = b_ * NH + h;
            const float v = acc[i][r] + bb;
            if (isV) vth[(size_t)bh * (HEAD * 80) + d * 80 + s] = (_Float16)v;
            else     kh [(size_t)bh * (SEQS * HEAD) + s * HEAD + d] = (_Float16)v;
        }
}

// ---------------------------------------------------------------------------
// MFMA attention v2: persistent K/V per block.
// Grid (16, 64): block = one (b,h) x 256 q-rows (4 tiles of 64).
// ---------------------------------------------------------------------------
__global__ __launch_bounds__(256, 4) void attn_mfma(
    const _Float16* __restrict__ qh,   // [M][EMBED], 1/sqrt(80) pre-folded
    const _Float16* __restrict__ kh,   // [64][77][80]
    const _Float16* __restrict__ vth,  // [64][80][80]
    _Float16* __restrict__ oh)         // [M][EMBED]
{
    constexpr int LS = 88;             // f16 LDS row stride (80 data + 8 pad)
    __shared__ _Float16 lds[(80 + 80 + 64) * LS + 8];
    _Float16* Ks = lds;                // [80][LS]  rows 77..79 zeroed
    _Float16* Vt = lds + 80 * LS;      // [80][LS]
    _Float16* Ps = lds + 160 * LS;     // [64][LS]

    const int tid = threadIdx.x;
    const int wave = tid >> 6, lane = tid & 63;
    const int quad = lane >> 4, l16 = lane & 15;
    const int bh = blockIdx.y;
    const int b = bh >> 3, h = bh & 7;
    const size_t row0 = (size_t)b * SEQT + (size_t)blockIdx.x * 256;
    const half8 hz = {};

    const _Float16* qp = qh + (row0 + wave * 16 + l16) * EMBED + h * HEAD;

    half8 qa0 = *(const half8*)&qp[quad * 8];
    half8 qa1 = *(const half8*)&qp[32 + quad * 8];
    half8 qa2 = (quad < 2) ? *(const half8*)&qp[64 + quad * 8] : hz;

    for (int idx = tid; idx < 80 * 11; idx += 256) {
        const int s = idx / 11, c = idx % 11;
        half8 v = hz;
        if (s < SEQS && c < 10)
            v = *(const half8*)&kh[(size_t)bh * (SEQS * HEAD) + s * HEAD + c * 8];
        *(half8*)&Ks[s * LS + c * 8] = v;
    }
    for (int idx = tid; idx < 80 * 11; idx += 256) {
        const int d = idx / 11, c = idx % 11;
        half8 v = hz;
        if (c < 10)
            v = *(const half8*)&vth[(size_t)bh * (HEAD * 80) + d * 80 + c * 8];
        *(half8*)&Vt[d * LS + c * 8] = v;
    }
    __syncthreads();

    for (int t = 0; t < 4; ++t) {
        floatx4 accs[5] = {};
        #pragma unroll
        for (int st = 0; st < 5; ++st) {
            const _Float16* kr = &Ks[(st * 16 + l16) * LS];
            half8 b0 = *(const half8*)&kr[quad * 8];
            half8 b1 = *(const half8*)&kr[32 + quad * 8];
            half8 b2 = *(const half8*)&kr[64 + quad * 8];
            accs[st] = __builtin_amdgcn_mfma_f32_16x16x32_f16(qa0, b0, accs[st], 0, 0, 0);
            accs[st] = __builtin_amdgcn_mfma_f32_16x16x32_f16(qa1, b1, accs[st], 0, 0, 0);
            accs[st] = __builtin_amdgcn_mfma_f32_16x16x32_f16(qa2, b2, accs[st], 0, 0, 0);
        }
        if (l16 >= 13) {
            accs[4][0] = -1e30f; accs[4][1] = -1e30f;
            accs[4][2] = -1e30f; accs[4][3] = -1e30f;
        }

        float recip[4];
        #pragma unroll
        for (int r = 0; r < 4; ++r) {
            float m = accs[0][r];
            #pragma unroll
            for (int st = 1; st < 5; ++st) m = fmaxf(m, accs[st][r]);
            m = fmaxf(m, __shfl_xor(m, 1));
            m = fmaxf(m, __shfl_xor(m, 2));
            m = fmaxf(m, __shfl_xor(m, 4));
            m = fmaxf(m, __shfl_xor(m, 8));
            float l = 0.f;
            const int row = wave * 16 + quad * 4 + r;
            #pragma unroll
            for (int st = 0; st < 5; ++st) {
                float e = __expf(accs[st][r] - m);
                l += e;
                Ps[row * LS + st * 16 + l16] = (_Float16)e;
            }
            l += __shfl_xor(l, 1);
            l += __shfl_xor(l, 2);
            l += __shfl_xor(l, 4);
            l += __shfl_xor(l, 8);
            recip[r] = 1.0f / l;
        }
        __syncthreads();

        half8 qn0 = hz, qn1 = hz, qn2 = hz;
        if (t < 3) {
            const _Float16* qn = qp + (size_t)(t + 1) * 64 * EMBED;
            qn0 = *(const half8*)&qn[quad * 8];
            qn1 = *(const half8*)&qn[32 + quad * 8];
            if (quad < 2) qn2 = *(const half8*)&qn[64 + quad * 8];
        }

        const _Float16* pr = &Ps[(wave * 16 + l16) * LS];
        half8 pa0 = *(const half8*)&pr[quad * 8];
        half8 pa1 = *(const half8*)&pr[32 + quad * 8];
        half8 pa2 = (quad < 2) ? *(const half8*)&pr[64 + quad * 8] : hz;
        __syncthreads();

        floatx4 acco[5] = {};
        #pragma unroll
        for (int dt = 0; dt < 5; ++dt) {
            const _Float16* vr = &Vt[(dt * 16 + l16) * LS];
            half8 b0 = *(const half8*)&vr[quad * 8];
            half8 b1 = *(const half8*)&vr[32 + quad * 8];
            half8 b2 = *(const half8*)&vr[64 + quad * 8];
            acco[dt] = __builtin_amdgcn_mfma_f32_16x16x32_f16(pa0, b0, acco[dt], 0, 0, 0);
            acco[dt] = __builtin_amdgcn_mfma_f32_16x16x32_f16(pa1, b1, acco[dt], 0, 0, 0);
            acco[dt] = __builtin_amdgcn_mfma_f32_16x16x32_f16(pa2, b2, acco[dt], 0, 0, 0);
        }

        #pragma unroll
        for (int r = 0; r < 4; ++r) {
            const size_t grow = row0 + t * 64 + wave * 16 + quad * 4 + r;
            #pragma unroll
            for (int dt = 0; dt < 5; ++dt)
                oh[grow * EMBED + h * HEAD + dt * 16 + l16] =
                    (_Float16)(acco[dt][r] * recip[r]);
        }

        qa0 = qn0; qa1 = qn1; qa2 = qn2;
    }
}

// ---------------------------------------------------------------------------
extern "C" void kernel_launch(void* const* d_in, const int* in_sizes, int n_in,
                              void* d_out, int out_size, void* d_ws, size_t ws_size,
                              hipStream_t stream)
{
    const float* x  = (const float*)d_in[0];
    const float* y  = (const float*)d_in[1];
    const float* Wq = (const float*)d_in[2];
    const float* bq = (const float*)d_in[3];
    const float* Wk = (const float*)d_in[4];
    const float* bk = (const float*)d_in[5];
    const float* Wv = (const float*)d_in[6];
    const float* bv = (const float*)d_in[7];
    const float* Wo = (const float*)d_in[8];
    const float* bo = (const float*)d_in[9];
    float* out = (float*)d_out;

    const size_t ME = (size_t)MROWS * EMBED;
    _Float16* qh  = (_Float16*)d_ws;                          // [M][640]
    _Float16* ah  = qh + ME;                                  // [M][640]
    _Float16* kh  = ah + ME;                                  // [64][77][80]
    _Float16* vth = kh  + (size_t)BATCH * NH * SEQS * HEAD;   // [64][80][80]
    _Float16* wqt = vth + (size_t)BATCH * NH * HEAD * 80;     // [640][640]
    _Float16* wot = wqt + (size_t)EMBED * EMBED;              // [640][640]
    _Float16* yh  = wot + (size_t)EMBED * EMBED;              // [640][768]
    _Float16* wkt = yh  + (size_t)640 * CROSS;                // [640][768]
    _Float16* wvt = wkt + (size_t)EMBED * CROSS;              // [640][768]

    // prep (2 launches)
    transpose_all<<<dim3(EMBED / 32, CROSS / 32, 4), dim3(32, 8), 0, stream>>>(
        Wq, Wo, Wk, Wv, wqt, wot, wkt, wvt);
    cvt_y_zero<<<dim3(440), 256, 0, stream>>>(y, yh, vth);

    // 1) Q = (x @ Wq + bq) * 1/sqrt(80), fused fp32->f16 cast (v7 pipeline)
    gemm_q<<<dim3(EMBED / 128, MROWS / 128), 256, 0, stream>>>(x, wqt, bq, qh);
    // 2) K,V projections via MFMA -> attention layouts
    kv_gemm<<<dim3(EMBED / 64, 640 / 64, 2), 256, 0, stream>>>(
        yh, wkt, wvt, bk, bv, kh, vth);
    // 3) MFMA attention: persistent K/V, 256 q-rows per block
    attn_mfma<<<dim3(SEQT / 256, BATCH * NH), 256, 0, stream>>>(qh, kh, vth, ah);
    // 4) out = attn_out @ Wo + bo (fp32 out, v6 gemm)
    gemm_f16<false><<<dim3(EMBED / 128, MROWS / 128), 256, 0, stream>>>(
        ah, wot, bo, out, MROWS, EMBED, EMBED, 1.0f);
}

// Round 8
// 286.454 us; speedup vs baseline: 1.0748x; 1.0748x over previous
//
#include <hip/hip_runtime.h>
#include <hip/hip_bf16.h>
#include <hip/hip_fp16.h>

#define EMBED 640
#define CROSS 768
#define NH 8
#define HEAD 80
#define BATCH 8
#define SEQT 4096
#define SEQS 77
#define MROWS (BATCH * SEQT)

typedef _Float16 half8 __attribute__((ext_vector_type(8)));
typedef float floatx4 __attribute__((ext_vector_type(4)));

__device__ __forceinline__ void lds_load16(const void* g, void* l) {
    __builtin_amdgcn_global_load_lds(
        (const __attribute__((address_space(1))) void*)g,
        (__attribute__((address_space(3))) void*)l, 16, 0, 0);
}

// ---------------------------------------------------------------------------
// fp32 -> f16 cast, 8 elems/thread (exact grids used).
// ---------------------------------------------------------------------------
__global__ __launch_bounds__(256) void cvt_f32_f16(
    const float* __restrict__ in, _Float16* __restrict__ out)
{
    size_t i = ((size_t)blockIdx.x * 256 + threadIdx.x) * 8;
    float4 a = *(const float4*)&in[i];
    float4 b = *(const float4*)&in[i + 4];
    half8 h;
    h[0] = (_Float16)a.x; h[1] = (_Float16)a.y;
    h[2] = (_Float16)a.z; h[3] = (_Float16)a.w;
    h[4] = (_Float16)b.x; h[5] = (_Float16)b.y;
    h[6] = (_Float16)b.z; h[7] = (_Float16)b.w;
    *(half8*)&out[i] = h;
}

// ---------------------------------------------------------------------------
// All four weight transposes in one launch. z: 0=Wq 1=Wo 2=Wk 3=Wv.
// ---------------------------------------------------------------------------
__global__ __launch_bounds__(256) void transpose_all(
    const float* __restrict__ Wq, const float* __restrict__ Wo,
    const float* __restrict__ Wk, const float* __restrict__ Wv,
    _Float16* __restrict__ wqt, _Float16* __restrict__ wot,
    _Float16* __restrict__ wkt, _Float16* __restrict__ wvt)
{
    __shared__ float t[32][33];
    const int z = blockIdx.z;
    const float* W;  _Float16* Wt;  int K;
    if      (z == 0) { W = Wq; Wt = wqt; K = EMBED; }
    else if (z == 1) { W = Wo; Wt = wot; K = EMBED; }
    else if (z == 2) { W = Wk; Wt = wkt; K = CROSS; }
    else             { W = Wv; Wt = wvt; K = CROSS; }
    const int N = EMBED;
    const int k0 = blockIdx.y * 32, n0 = blockIdx.x * 32;
    if (k0 >= K) return;
    for (int r = threadIdx.y; r < 32; r += 8)
        t[r][threadIdx.x] = W[(size_t)(k0 + r) * N + n0 + threadIdx.x];
    __syncthreads();
    for (int r = threadIdx.y; r < 32; r += 8)
        Wt[(size_t)(n0 + r) * K + k0 + threadIdx.x] = (_Float16)t[threadIdx.x][r];
}

// ---------------------------------------------------------------------------
// y [616*768] fp32 -> yh [640][768] f16 (rows 616+ zeroed)  AND  vth zero.
// ---------------------------------------------------------------------------
__global__ __launch_bounds__(256) void cvt_y_zero(
    const float* __restrict__ y, _Float16* __restrict__ yh,
    _Float16* __restrict__ vth)
{
    const size_t i = (size_t)blockIdx.x * 256 + threadIdx.x;
    if (i < (size_t)640 * CROSS / 8) {
        const size_t e = i * 8;
        half8 h = {};
        if (e < (size_t)BATCH * SEQS * CROSS) {
            float4 a = *(const float4*)&y[e];
            float4 b = *(const float4*)&y[e + 4];
            h[0] = (_Float16)a.x; h[1] = (_Float16)a.y;
            h[2] = (_Float16)a.z; h[3] = (_Float16)a.w;
            h[4] = (_Float16)b.x; h[5] = (_Float16)b.y;
            h[6] = (_Float16)b.z; h[7] = (_Float16)b.w;
        }
        *(half8*)&yh[e] = h;
    } else {
        const size_t j = (i - (size_t)640 * CROSS / 8) * 8;
        *(half8*)&vth[j] = (half8){};
    }
}

// ---------------------------------------------------------------------------
// f16 MFMA GEMM v8: C = A[M,K] @ Bt[N,K]^T + bias, then *scale.
// 512 threads / 8 waves per block (4M x 2N; 32x64 output per wave) -> at the
// same 64 KB LDS / 2 blocks/CU this gives 4 waves/SIMD (vs v6's 2): doubled
// TLP for latency hiding. BK=64 double-buffer, stage-first + counted
// vmcnt(4) (each wave stages 2 A + 2 B gload_lds per tile; next tile's 4
// stay in flight across the barrier). 8-slot XOR swizzle both-sides
// (row&7 == l16&7 on the read side since wm % 8 == 0). XCD-aware remap.
// ---------------------------------------------------------------------------
template <bool HALF_OUT>
__global__ __launch_bounds__(512) void gemm_f16(
    const _Float16* __restrict__ A,   // [M,K] f16
    const _Float16* __restrict__ Bt,  // [N,K] f16
    const float* __restrict__ bias,
    void* __restrict__ Cout, int M, int N, int K, float scale)
{
    __shared__ _Float16 As[2][128 * 64];
    __shared__ _Float16 Bs[2][128 * 64];

    const int tid  = threadIdx.x;
    const int wave = tid >> 6;        // 0..7
    const int lane = tid & 63;
    const int quad = lane >> 4;
    const int l16  = lane & 15;

    // XCD-aware remap: the gridDim.x n-tiles of one m-panel -> same XCD.
    const int l   = blockIdx.y * gridDim.x + blockIdx.x;
    const int inner = l >> 3;
    const int p   = (l & 7) + 8 * (inner / gridDim.x);
    const int nt  = inner % gridDim.x;
    const int m0 = p * 128, n0 = nt * 128;
    const int wm = (wave >> 1) * 32;  // 4 wave-rows of 32
    const int wn = (wave & 1) * 64;   // 2 wave-cols of 64

    // staging: wave w, instr q in {0,1} fills 8 rows (1 KB) starting at
    // row w*16 + q*8; lane l -> row + (l>>3), slot l&7 holds global chunk
    // (l&7) ^ (l>>3)  [LDS slot s of row r holds global chunk s ^ (r&7)].
    const int srow = wave * 16 + (lane >> 3);          // + q*8
    const int sch  = ((lane & 7) ^ (lane >> 3)) * 8;   // pre-swizzled chunk
    const _Float16* gA[2];
    const _Float16* gB[2];
    #pragma unroll
    for (int q = 0; q < 2; ++q) {
        gA[q] = &A [(size_t)(m0 + srow + q * 8) * K + sch];
        gB[q] = &Bt[(size_t)(n0 + srow + q * 8) * K + sch];
    }

    const int NT = K / 64;   // 10

    auto stage = [&](int t, int bf) {
        const size_t off = (size_t)t * 64;
        #pragma unroll
        for (int q = 0; q < 2; ++q) {
            lds_load16(gA[q] + off, &As[bf][(wave * 2 + q) * 512]);
            lds_load16(gB[q] + off, &Bs[bf][(wave * 2 + q) * 512]);
        }
    };
    stage(0, 0);             // 4 loads in flight per wave

    floatx4 acc[2][4] = {};

    for (int t = 0; t < NT; ++t) {
        const int bf = t & 1;
        if (t + 1 < NT) {
            stage(t + 1, bf ^ 1);                       // 8 outstanding
            asm volatile("s_waitcnt vmcnt(4)" ::: "memory");  // tile t landed
        } else {
            asm volatile("s_waitcnt vmcnt(0)" ::: "memory");
        }
        __builtin_amdgcn_s_barrier();       // all waves' tile t visible
        __builtin_amdgcn_sched_barrier(0);

        const _Float16* as = As[bf];
        const _Float16* bs = Bs[bf];
        __builtin_amdgcn_s_setprio(1);
        #pragma unroll
        for (int k = 0; k < 2; ++k) {
            half8 a[2], b[4];
            #pragma unroll
            for (int i = 0; i < 2; ++i)
                a[i] = *(const half8*)&as[(wm + i * 16 + l16) * 64 +
                                          (((k * 4 + quad) ^ (l16 & 7)) * 8)];
            #pragma unroll
            for (int j = 0; j < 4; ++j)
                b[j] = *(const half8*)&bs[(wn + j * 16 + l16) * 64 +
                                          (((k * 4 + quad) ^ (l16 & 7)) * 8)];
            #pragma unroll
            for (int i = 0; i < 2; ++i)
                #pragma unroll
                for (int j = 0; j < 4; ++j)
                    acc[i][j] = __builtin_amdgcn_mfma_f32_16x16x32_f16(
                        a[i], b[j], acc[i][j], 0, 0, 0);
        }
        __builtin_amdgcn_s_setprio(0);

        asm volatile("s_waitcnt lgkmcnt(0)" ::: "memory");
        __builtin_amdgcn_sched_barrier(0);
        __builtin_amdgcn_s_barrier();       // tile-t buffer free to restage
    }

    float bcol[4];
    #pragma unroll
    for (int j = 0; j < 4; ++j) bcol[j] = bias[n0 + wn + j * 16 + l16];
    #pragma unroll
    for (int i = 0; i < 2; ++i)
        #pragma unroll
        for (int r = 0; r < 4; ++r) {
            const int m = m0 + wm + i * 16 + quad * 4 + r;
            #pragma unroll
            for (int j = 0; j < 4; ++j) {
                float v = (acc[i][j][r] + bcol[j]) * scale;
                const size_t off = (size_t)m * N + n0 + wn + j * 16 + l16;
                if (HALF_OUT) ((_Float16*)Cout)[off] = (_Float16)v;
                else          ((float*)Cout)[off] = v;
            }
        }
}

// ---------------------------------------------------------------------------
// K/V projection via MFMA. 64x64 tiles, 4 waves (wave w = cols w*16..w*16+15).
// ---------------------------------------------------------------------------
__global__ __launch_bounds__(256) void kv_gemm(
    const _Float16* __restrict__ yh,
    const _Float16* __restrict__ Wkt, const _Float16* __restrict__ Wvt,
    const float* __restrict__ bk, const float* __restrict__ bv,
    _Float16* __restrict__ kh, _Float16* __restrict__ vth)
{
    __shared__ _Float16 As[64 * 32];
    __shared__ _Float16 Bs[64 * 32];

    const int tid = threadIdx.x;
    const int wave = tid >> 6, lane = tid & 63;
    const int quad = lane >> 4, l16 = lane & 15;
    const int m0 = blockIdx.y * 64, n0 = blockIdx.x * 64;
    const bool isV = blockIdx.z != 0;
    const _Float16* Bt = isV ? Wvt : Wkt;
    const float* bias  = isV ? bv : bk;

    const int row = tid >> 2;        // 0..63
    const int kch = (tid & 3) * 8;   // k chunk (8 f16 = 16 B)

    floatx4 acc[4] = {};

    for (int k0 = 0; k0 < CROSS; k0 += 32) {
        lds_load16(&yh[(size_t)(m0 + row) * CROSS + k0 + kch], &As[wave * 512]);
        lds_load16(&Bt[(size_t)(n0 + row) * CROSS + k0 + kch], &Bs[wave * 512]);
        __syncthreads();
        half8 b = *(const half8*)&Bs[(wave * 16 + l16) * 32 + quad * 8];
        #pragma unroll
        for (int i = 0; i < 4; ++i) {
            half8 a = *(const half8*)&As[(i * 16 + l16) * 32 + quad * 8];
            acc[i] = __builtin_amdgcn_mfma_f32_16x16x32_f16(a, b, acc[i], 0, 0, 0);
        }
        __syncthreads();
    }

    const int n = n0 + wave * 16 + l16;     // 0..639
    const int h = n / HEAD, d = n % HEAD;
    const float bb = bias[n];
    #pragma unroll
    for (int i = 0; i < 4; ++i)
        #pragma unroll
        for (int r = 0; r < 4; ++r) {
            const int m = m0 + i * 16 + quad * 4 + r;
            if (m >= BATCH * SEQS) continue;
            const int b_ = m / SEQS, s = m % SEQS;
            const int bh = b_ * NH + h;
            const float v = acc[i][r] + bb;
            if (isV) vth[(size_t)bh * (HEAD * 80) + d * 80 + s] = (_Float16)v;
            else     kh [(size_t)bh * (SEQS * HEAD) + s * HEAD + d] = (_Float16)v;
        }
}

// ---------------------------------------------------------------------------
// MFMA attention v2: persistent K/V per block.
// Grid (16, 64): block = one (b,h) x 256 q-rows (4 tiles of 64).
// ---------------------------------------------------------------------------
__global__ __launch_bounds__(256, 4) void attn_mfma(
    const _Float16* __restrict__ qh,   // [M][EMBED], 1/sqrt(80) pre-folded
    const _Float16* __restrict__ kh,   // [64][77][80]
    const _Float16* __restrict__ vth,  // [64][80][80]
    _Float16* __restrict__ oh)         // [M][EMBED]
{
    constexpr int LS = 88;             // f16 LDS row stride (80 data + 8 pad)
    __shared__ _Float16 lds[(80 + 80 + 64) * LS + 8];
    _Float16* Ks = lds;                // [80][LS]  rows 77..79 zeroed
    _Float16* Vt = lds + 80 * LS;      // [80][LS]
    _Float16* Ps = lds + 160 * LS;     // [64][LS]

    const int tid = threadIdx.x;
    const int wave = tid >> 6, lane = tid & 63;
    const int quad = lane >> 4, l16 = lane & 15;
    const int bh = blockIdx.y;
    const int b = bh >> 3, h = bh & 7;
    const size_t row0 = (size_t)b * SEQT + (size_t)blockIdx.x * 256;
    const half8 hz = {};

    const _Float16* qp = qh + (row0 + wave * 16 + l16) * EMBED + h * HEAD;

    half8 qa0 = *(const half8*)&qp[quad * 8];
    half8 qa1 = *(const half8*)&qp[32 + quad * 8];
    half8 qa2 = (quad < 2) ? *(const half8*)&qp[64 + quad * 8] : hz;

    for (int idx = tid; idx < 80 * 11; idx += 256) {
        const int s = idx / 11, c = idx % 11;
        half8 v = hz;
        if (s < SEQS && c < 10)
            v = *(const half8*)&kh[(size_t)bh * (SEQS * HEAD) + s * HEAD + c * 8];
        *(half8*)&Ks[s * LS + c * 8] = v;
    }
    for (int idx = tid; idx < 80 * 11; idx += 256) {
        const int d = idx / 11, c = idx % 11;
        half8 v = hz;
        if (c < 10)
            v = *(const half8*)&vth[(size_t)bh * (HEAD * 80) + d * 80 + c * 8];
        *(half8*)&Vt[d * LS + c * 8] = v;
    }
    __syncthreads();

    for (int t = 0; t < 4; ++t) {
        floatx4 accs[5] = {};
        #pragma unroll
        for (int st = 0; st < 5; ++st) {
            const _Float16* kr = &Ks[(st * 16 + l16) * LS];
            half8 b0 = *(const half8*)&kr[quad * 8];
            half8 b1 = *(const half8*)&kr[32 + quad * 8];
            half8 b2 = *(const half8*)&kr[64 + quad * 8];
            accs[st] = __builtin_amdgcn_mfma_f32_16x16x32_f16(qa0, b0, accs[st], 0, 0, 0);
            accs[st] = __builtin_amdgcn_mfma_f32_16x16x32_f16(qa1, b1, accs[st], 0, 0, 0);
            accs[st] = __builtin_amdgcn_mfma_f32_16x16x32_f16(qa2, b2, accs[st], 0, 0, 0);
        }
        if (l16 >= 13) {
            accs[4][0] = -1e30f; accs[4][1] = -1e30f;
            accs[4][2] = -1e30f; accs[4][3] = -1e30f;
        }

        float recip[4];
        #pragma unroll
        for (int r = 0; r < 4; ++r) {
            float m = accs[0][r];
            #pragma unroll
            for (int st = 1; st < 5; ++st) m = fmaxf(m, accs[st][r]);
            m = fmaxf(m, __shfl_xor(m, 1));
            m = fmaxf(m, __shfl_xor(m, 2));
            m = fmaxf(m, __shfl_xor(m, 4));
            m = fmaxf(m, __shfl_xor(m, 8));
            float l = 0.f;
            const int row = wave * 16 + quad * 4 + r;
            #pragma unroll
            for (int st = 0; st < 5; ++st) {
                float e = __expf(accs[st][r] - m);
                l += e;
                Ps[row * LS + st * 16 + l16] = (_Float16)e;
            }
            l += __shfl_xor(l, 1);
            l += __shfl_xor(l, 2);
            l += __shfl_xor(l, 4);
            l += __shfl_xor(l, 8);
            recip[r] = 1.0f / l;
        }
        __syncthreads();

        half8 qn0 = hz, qn1 = hz, qn2 = hz;
        if (t < 3) {
            const _Float16* qn = qp + (size_t)(t + 1) * 64 * EMBED;
            qn0 = *(const half8*)&qn[quad * 8];
            qn1 = *(const half8*)&qn[32 + quad * 8];
            if (quad < 2) qn2 = *(const half8*)&qn[64 + quad * 8];
        }

        const _Float16* pr = &Ps[(wave * 16 + l16) * LS];
        half8 pa0 = *(const half8*)&pr[quad * 8];
        half8 pa1 = *(const half8*)&pr[32 + quad * 8];
        half8 pa2 = (quad < 2) ? *(const half8*)&pr[64 + quad * 8] : hz;
        __syncthreads();

        floatx4 acco[5] = {};
        #pragma unroll
        for (int dt = 0; dt < 5; ++dt) {
            const _Float16* vr = &Vt[(dt * 16 + l16) * LS];
            half8 b0 = *(const half8*)&vr[quad * 8];
            half8 b1 = *(const half8*)&vr[32 + quad * 8];
            half8 b2 = *(const half8*)&vr[64 + quad * 8];
            acco[dt] = __builtin_amdgcn_mfma_f32_16x16x32_f16(pa0, b0, acco[dt], 0, 0, 0);
            acco[dt] = __builtin_amdgcn_mfma_f32_16x16x32_f16(pa1, b1, acco[dt], 0, 0, 0);
            acco[dt] = __builtin_amdgcn_mfma_f32_16x16x32_f16(pa2, b2, acco[dt], 0, 0, 0);
        }

        #pragma unroll
        for (int r = 0; r < 4; ++r) {
            const size_t grow = row0 + t * 64 + wave * 16 + quad * 4 + r;
            #pragma unroll
            for (int dt = 0; dt < 5; ++dt)
                oh[grow * EMBED + h * HEAD + dt * 16 + l16] =
                    (_Float16)(acco[dt][r] * recip[r]);
        }

        qa0 = qn0; qa1 = qn1; qa2 = qn2;
    }
}

// ---------------------------------------------------------------------------
extern "C" void kernel_launch(void* const* d_in, const int* in_sizes, int n_in,
                              void* d_out, int out_size, void* d_ws, size_t ws_size,
                              hipStream_t stream)
{
    const float* x  = (const float*)d_in[0];
    const float* y  = (const float*)d_in[1];
    const float* Wq = (const float*)d_in[2];
    const float* bq = (const float*)d_in[3];
    const float* Wk = (const float*)d_in[4];
    const float* bk = (const float*)d_in[5];
    const float* Wv = (const float*)d_in[6];
    const float* bv = (const float*)d_in[7];
    const float* Wo = (const float*)d_in[8];
    const float* bo = (const float*)d_in[9];
    float* out = (float*)d_out;

    const size_t ME = (size_t)MROWS * EMBED;
    _Float16* xh  = (_Float16*)d_ws;                          // [M][640]
    _Float16* qh  = xh + ME;                                  // [M][640]
    _Float16* ah  = qh + ME;                                  // [M][640]
    _Float16* kh  = ah + ME;                                  // [64][77][80]
    _Float16* vth = kh  + (size_t)BATCH * NH * SEQS * HEAD;   // [64][80][80]
    _Float16* wqt = vth + (size_t)BATCH * NH * HEAD * 80;     // [640][640]
    _Float16* wot = wqt + (size_t)EMBED * EMBED;              // [640][640]
    _Float16* yh  = wot + (size_t)EMBED * EMBED;              // [640][768]
    _Float16* wkt = yh  + (size_t)640 * CROSS;                // [640][768]
    _Float16* wvt = wkt + (size_t)EMBED * CROSS;              // [640][768]

    // prep (3 launches)
    transpose_all<<<dim3(EMBED / 32, CROSS / 32, 4), dim3(32, 8), 0, stream>>>(
        Wq, Wo, Wk, Wv, wqt, wot, wkt, wvt);
    cvt_y_zero<<<dim3(440), 256, 0, stream>>>(y, yh, vth);
    cvt_f32_f16<<<dim3(ME / (256 * 8)), 256, 0, stream>>>(x, xh);

    // 1) Q = (x @ Wq + bq) * 1/sqrt(80), f16 out (v8 gemm, 512 thr)
    gemm_f16<true><<<dim3(EMBED / 128, MROWS / 128), 512, 0, stream>>>(
        xh, wqt, bq, qh, MROWS, EMBED, EMBED, 0.11180339887498949f);
    // 2) K,V projections via MFMA -> attention layouts
    kv_gemm<<<dim3(EMBED / 64, 640 / 64, 2), 256, 0, stream>>>(
        yh, wkt, wvt, bk, bv, kh, vth);
    // 3) MFMA attention: persistent K/V, 256 q-rows per block
    attn_mfma<<<dim3(SEQT / 256, BATCH * NH), 256, 0, stream>>>(qh, kh, vth, ah);
    // 4) out = attn_out @ Wo + bo (fp32 out, v8 gemm, 512 thr)
    gemm_f16<false><<<dim3(EMBED / 128, MROWS / 128), 512, 0, stream>>>(
        ah, wot, bo, out, MROWS, EMBED, EMBED, 1.0f);
}